// Round 5
// baseline (52.693 us; speedup 1.0000x reference)
//
#include <hip/hip_runtime.h>

#define PAD 4
#define B_ 64
#define C_ 9
#define H_ 256
#define W_ 256
#define PEXT 264           // padded extent (both axes)
#define HTILE 16           // rows per half-tile
#define SROWS 18           // max staged rows per half-tile
#define NBLK (B_ * C_ * (H_ / 32))   // 4608, divisible by 8

// Block = 512 threads (8 waves) owning a 32-row x 256-col tile of one plane,
// processed as two 16-row halves with double-buffered LDS staging:
//   stage(h0); barrier; stage(h1); compute(h0); barrier; compute(h1)
// so half the HBM staging latency hides under compute.
//
// LDS holds PURE source rows (no pad columns): x-replicate padding is folded
// into the tap weights (when both taps clamp to the same source column,
// merge the weights and clamp the read column), so staging is pure
// global_load_lds and every tap pair stays a fused ds_read2_b32 (c, c+1).
// y-replicate handled by clamping the staged source row; grid_sample
// zeros-padding by zeroing weights vs padded extent [0,263].
// Coordinate math identical to rounds 1-4: ix = 0.5 + shift + j*(262/255).
__global__ __launch_bounds__(512, 8) void RandomShiftsAug_kernel(
    const float* __restrict__ x,
    const int* __restrict__ shift_x,
    const int* __restrict__ shift_y,
    float* __restrict__ out)
{
    __shared__ float sm[2][SROWS][W_];   // 36864 B -> 4 blocks/CU, 32 waves/CU

    const int tid  = threadIdx.x;
    const int lane = tid & 63;
    const int wv   = tid >> 6;           // 0..7

    // XCD-bijective swizzle: adjacent work ids land on the same XCD so the
    // ~1.5-row staging overlap between vertical neighbors hits that XCD's L2.
    const int wid  = (blockIdx.x & 7) * (NBLK / 8) + (blockIdx.x >> 3);

    const int bc   = wid >> 3;           // plane id (b*C + c)
    const int I0   = (wid & 7) << 5;     // 32-row tile base
    const int b    = bc / C_;

    const float STEP = 262.0f / 255.0f;
    const float sx = (float)shift_x[b];
    const float sy = (float)shift_y[b];
    const float xbase = 0.5f + sx;
    const float ybase = 0.5f + sy;

    const float* __restrict__ plane = x + (size_t)bc * (size_t)(H_ * W_);

    // staged padded-row range per half (block-uniform)
    int srb[2], srn[2];
    #pragma unroll
    for (int h = 0; h < 2; ++h) {
        const int i0 = I0 + h * HTILE;
        const int lo = (int)floorf(fmaf((float)i0, STEP, ybase));
        const int hi = (int)floorf(fmaf((float)(i0 + HTILE - 1), STEP, ybase)) + 1;
        srb[h] = lo;
        srn[h] = hi - lo + 1;            // 17 or 18
    }

    // ---- x-side precompute: 4 interleaved cols/lane, pad folded into weights
    float wx0[4], wx1[4];
    int cx[4];
    #pragma unroll
    for (int c = 0; c < 4; ++c) {
        const int j = lane + 64 * c;
        const float ixv = fmaf((float)j, STEP, xbase);
        const float fx  = floorf(ixv);
        const int   px0 = (int)fx;              // >= 0 always (ix >= 0.5)
        float w1 = ixv - fx;
        float w0 = 1.0f - w1;
        if (px0 > PEXT - 1)     w0 = 0.0f;      // zeros padding
        if (px0 + 1 > PEXT - 1) w1 = 0.0f;
        const int s = px0 - PAD;                // desired source col of tap0
        if (s < 0)    { w0 += w1; w1 = 0.0f; }  // both taps -> src col 0
        if (s >= 255) { w1 += w0; w0 = 0.0f; }  // both taps -> src col 255
        cx[c]  = min(max(s, 0), 254);           // fused pair reads (cx, cx+1)
        wx0[c] = w0;
        wx1[c] = w1;
    }

    // ---- stage: pure global_load_lds, 16B/lane, one row per wave-iteration
    auto stage = [&](int h) {
        const int base = srb[h];
        const int n    = srn[h];
        for (int s = wv; s < n; s += 8) {
            const int rs = min(max(base + s - PAD, 0), H_ - 1);
            const float* src = plane + rs * W_ + lane * 4;
            __builtin_amdgcn_global_load_lds(
                (const __attribute__((address_space(1))) void*)src,
                (__attribute__((address_space(3))) void*)&sm[h][s][0],
                16, 0, 0);
        }
    };

    // ---- compute: 2 rows per wave, 4 cols per lane
    auto compute = [&](int h) {
        const int i0 = I0 + h * HTILE;
        #pragma unroll
        for (int m = 0; m < 2; ++m) {
            const int i = i0 + wv * 2 + m;                  // wave-uniform row
            const float iyv = fmaf((float)i, STEP, ybase);
            const float fy  = floorf(iyv);
            const int   py0 = (int)fy;
            float wy1 = iyv - fy;
            float wy0 = 1.0f - wy1;
            if (py0 > PEXT - 1)     wy0 = 0.0f;
            if (py0 + 1 > PEXT - 1) wy1 = 0.0f;
            const int s0 = py0 - srb[h];                    // in [0, srn-2]
            const float* __restrict__ r0p = &sm[h][s0][0];
            const float* __restrict__ r1p = &sm[h][s0 + 1][0];
            float* __restrict__ orow = out + ((size_t)(bc * H_ + i)) * (size_t)W_;

            #pragma unroll
            for (int c = 0; c < 4; ++c) {
                const int rd = cx[c];
                const float v00 = r0p[rd], v01 = r0p[rd + 1];   // ds_read2_b32
                const float v10 = r1p[rd], v11 = r1p[rd + 1];   // ds_read2_b32
                const float a0 = fmaf(v00, wx0[c], v01 * wx1[c]);
                const float a1 = fmaf(v10, wx0[c], v11 * wx1[c]);
                orow[lane + 64 * c] = fmaf(a0, wy0, a1 * wy1);
            }
        }
    };

    stage(0);
    __syncthreads();      // buf0 ready
    stage(1);             // issue h1 loads -> latency hides under compute(h0)
    compute(0);
    __syncthreads();      // buf1 ready (drains vmcnt)
    compute(1);
}

extern "C" void kernel_launch(void* const* d_in, const int* in_sizes, int n_in,
                              void* d_out, int out_size, void* d_ws, size_t ws_size,
                              hipStream_t stream) {
    const float* x       = (const float*)d_in[0];
    const int*   shift_x = (const int*)d_in[1];
    const int*   shift_y = (const int*)d_in[2];
    float*       out     = (float*)d_out;

    RandomShiftsAug_kernel<<<NBLK, 512, 0, stream>>>(x, shift_x, shift_y, out);
}